// Round 3
// baseline (892.239 us; speedup 1.0000x reference)
//
#include <hip/hip_runtime.h>
#include <hip/hip_bf16.h>

typedef __hip_bfloat16 bf16;
typedef __bf16  bf16x8 __attribute__((ext_vector_type(8)));
typedef float   f32x4  __attribute__((ext_vector_type(4)));

static constexpr int DMODEL = 1024;
static constexpr int NHEADS = 16;
static constexpr int DHEAD  = 64;
static constexpr int BATCH  = 2;
static constexpr int SLQ    = 1024;
static constexpr int SLK    = 2048;
static constexpr size_t OUTQ = (size_t)BATCH * SLQ * DMODEL;   // out elems (f32)

// ---------------------------------------------------------------------------
// Stage 8 contiguous elements into LDS as bf16 (converting if source is f32).
// All call sites guarantee 16B (bf16) / 32B-span (f32: two 16B loads) align.
// ---------------------------------------------------------------------------
__device__ __forceinline__ void stage8(unsigned short* dst, const bf16* src) {
    *(int4*)dst = *(const int4*)src;
}
__device__ __forceinline__ void stage8(unsigned short* dst, const float* src) {
    const float4 a = *(const float4*)(src);
    const float4 b = *(const float4*)(src + 4);
    bf16 h[8];
    h[0] = __float2bfloat16(a.x); h[1] = __float2bfloat16(a.y);
    h[2] = __float2bfloat16(a.z); h[3] = __float2bfloat16(a.w);
    h[4] = __float2bfloat16(b.x); h[5] = __float2bfloat16(b.y);
    h[6] = __float2bfloat16(b.z); h[7] = __float2bfloat16(b.w);
    *(int4*)dst = *(const int4*)h;
}

__device__ __forceinline__ void store_one(bf16* p, float v) { *p = __float2bfloat16(v); }
__device__ __forceinline__ void store_one(float* p, float v) { *p = v; }

// ---------------------------------------------------------------------------
// Core 64x64 tile GEMM:  C_tile = A_tile (64 x K) * B_tile^T (K x 64)
// 256 threads = 4 waves in 2x2; each wave a 32x32 sub-tile via 2x2
// v_mfma_f32_16x16x32_bf16 (m92-verified structure). Sources f32 or bf16.
// A/B frag: elem[m = lane&15][k = (lane>>4)*8 + j]  (ds_read_b128)
// C/D frag: col = lane&15, row = (lane>>4)*4 + reg
// ---------------------------------------------------------------------------
template <typename TA, typename TB>
__device__ __forceinline__ void gemm_core(const TA* __restrict__ At, int lda,
                                          const TB* __restrict__ Bt, int ldb,
                                          int K, f32x4 acc[2][2])
{
    __shared__ __align__(16) unsigned short As[64][40];
    __shared__ __align__(16) unsigned short Bs[64][40];
    const int tid  = threadIdx.x;
    const int lane = tid & 63;
    const int wave = tid >> 6;
    const int wr   = (wave >> 1) * 32;
    const int wc   = (wave & 1) * 32;
    const int lrow = lane & 15;
    const int koff = (lane >> 4) * 8;
    const int srow   = tid >> 2;
    const int schunk = (tid & 3) * 8;

    for (int kt = 0; kt < K; kt += 32) {
        stage8(&As[srow][schunk], At + (size_t)srow * lda + kt + schunk);
        stage8(&Bs[srow][schunk], Bt + (size_t)srow * ldb + kt + schunk);
        __syncthreads();
        bf16x8 a0 = *(const bf16x8*)(&As[wr      + lrow][koff]);
        bf16x8 a1 = *(const bf16x8*)(&As[wr + 16 + lrow][koff]);
        bf16x8 b0 = *(const bf16x8*)(&Bs[wc      + lrow][koff]);
        bf16x8 b1 = *(const bf16x8*)(&Bs[wc + 16 + lrow][koff]);
        acc[0][0] = __builtin_amdgcn_mfma_f32_16x16x32_bf16(a0, b0, acc[0][0], 0, 0, 0);
        acc[0][1] = __builtin_amdgcn_mfma_f32_16x16x32_bf16(a0, b1, acc[0][1], 0, 0, 0);
        acc[1][0] = __builtin_amdgcn_mfma_f32_16x16x32_bf16(a1, b0, acc[1][0], 0, 0, 0);
        acc[1][1] = __builtin_amdgcn_mfma_f32_16x16x32_bf16(a1, b1, acc[1][1], 0, 0, 0);
        __syncthreads();
    }
}

// ---------------------------------------------------------------------------
// Projection:  C[M x N] = A[M x K] * W[N x K]^T + bias.  W/bias are f32.
// TA: f32 input or bf16 intermediate; TC: bf16 intermediate or f32 final out.
// ---------------------------------------------------------------------------
template <typename TA, typename TC>
__global__ __launch_bounds__(256)
void k_proj(const TA* __restrict__ A, const float* __restrict__ W,
            const float* __restrict__ bias, TC* __restrict__ C, int K, int N)
{
    const int m0 = blockIdx.x * 64;
    const int n0 = blockIdx.y * 64;
    f32x4 z = {0.f, 0.f, 0.f, 0.f};
    f32x4 acc[2][2] = {{z, z}, {z, z}};
    gemm_core(A + (size_t)m0 * K, K, W + (size_t)n0 * K, K, K, acc);
    const int lane = threadIdx.x & 63;
    const int wave = threadIdx.x >> 6;
    const int wr = (wave >> 1) * 32, wc = (wave & 1) * 32;
#pragma unroll
    for (int i = 0; i < 2; ++i)
#pragma unroll
        for (int j = 0; j < 2; ++j) {
            const int col = n0 + wc + j * 16 + (lane & 15);
            const float bv = bias[col];
#pragma unroll
            for (int r = 0; r < 4; ++r) {
                const int row = m0 + wr + i * 16 + (lane >> 4) * 4 + r;
                store_one(&C[(size_t)row * N + col], acc[i][j][r] + bv);
            }
        }
}

// ---------------------------------------------------------------------------
// V projection with per-head transposed output: Vt[(b*H+h)*64 + d][k]  (bf16)
// ---------------------------------------------------------------------------
__global__ __launch_bounds__(256)
void k_projV(const float* __restrict__ A, const float* __restrict__ W,
             const float* __restrict__ bias, bf16* __restrict__ Vt)
{
    const int m0 = blockIdx.x * 64;
    const int n0 = blockIdx.y * 64;
    f32x4 z = {0.f, 0.f, 0.f, 0.f};
    f32x4 acc[2][2] = {{z, z}, {z, z}};
    gemm_core(A + (size_t)m0 * DMODEL, DMODEL, W + (size_t)n0 * DMODEL, DMODEL, DMODEL, acc);
    const int lane = threadIdx.x & 63;
    const int wave = threadIdx.x >> 6;
    const int wr = (wave >> 1) * 32, wc = (wave & 1) * 32;
#pragma unroll
    for (int i = 0; i < 2; ++i)
#pragma unroll
        for (int j = 0; j < 2; ++j) {
            const int col = n0 + wc + j * 16 + (lane & 15);
            const float bv = bias[col];
            const int h = col >> 6, d = col & 63;
            const int mb = m0 + wr + i * 16 + (lane >> 4) * 4;  // multiple of 4
            const int b = mb >> 11;
            const int kk = mb & 2047;
            bf16* dst = Vt + ((size_t)(b * NHEADS + h) * DHEAD + d) * SLK + kk;
#pragma unroll
            for (int r = 0; r < 4; ++r)
                dst[r] = __float2bfloat16(acc[i][j][r] + bv);
        }
}

// ---------------------------------------------------------------------------
// Scores: S[b,h,q,k] = (Q.K^T)*0.125 + bias; mask==0 -> -1e9  (f32, in d_out)
// ---------------------------------------------------------------------------
__global__ __launch_bounds__(256)
void k_scores(const bf16* __restrict__ Qp, const bf16* __restrict__ Kp,
              const float* __restrict__ attn_bias, const int* __restrict__ mask,
              float* __restrict__ S)
{
    const int m0 = blockIdx.x * 64;
    const int n0 = blockIdx.y * 64;
    const int bh = blockIdx.z;
    const int b = bh >> 4;
    const int h = bh & 15;
    const bf16* A  = Qp + (size_t)b * SLQ * DMODEL + h * DHEAD + (size_t)m0 * DMODEL;
    const bf16* Bt = Kp + (size_t)b * SLK * DMODEL + h * DHEAD + (size_t)n0 * DMODEL;
    f32x4 z = {0.f, 0.f, 0.f, 0.f};
    f32x4 acc[2][2] = {{z, z}, {z, z}};
    gemm_core(A, DMODEL, Bt, DMODEL, DHEAD, acc);
    const int lane = threadIdx.x & 63;
    const int wave = threadIdx.x >> 6;
    const int wr = (wave >> 1) * 32, wc = (wave & 1) * 32;
#pragma unroll
    for (int i = 0; i < 2; ++i)
#pragma unroll
        for (int j = 0; j < 2; ++j) {
            const int kk = n0 + wc + j * 16 + (lane & 15);
#pragma unroll
            for (int r = 0; r < 4; ++r) {
                const int q = m0 + wr + i * 16 + (lane >> 4) * 4 + r;
                const size_t idx = ((size_t)bh * SLQ + q) * SLK + kk;
                float v = acc[i][j][r] * 0.125f + attn_bias[idx];
                if (mask[((size_t)b * SLQ + q) * SLK + kk] == 0) v = -1e9f;
                S[idx] = v;
            }
        }
}

// ---------------------------------------------------------------------------
// In-place row softmax over Lk=2048 (f32). One 256-thread block per row.
// ---------------------------------------------------------------------------
__global__ __launch_bounds__(256)
void k_softmax(float* __restrict__ S)
{
    const size_t row = blockIdx.x;
    float* p = S + row * SLK;
    const int tid = threadIdx.x;

    float4 v0 = *(const float4*)(p + tid * 8);
    float4 v1 = *(const float4*)(p + tid * 8 + 4);
    float f[8] = {v0.x, v0.y, v0.z, v0.w, v1.x, v1.y, v1.z, v1.w};
    float m = -3.0e38f;
#pragma unroll
    for (int j = 0; j < 8; ++j) m = fmaxf(m, f[j]);

    __shared__ float red[256];
    red[tid] = m;
    __syncthreads();
#pragma unroll
    for (int s = 128; s > 0; s >>= 1) {
        if (tid < s) red[tid] = fmaxf(red[tid], red[tid + s]);
        __syncthreads();
    }
    m = red[0];
    __syncthreads();

    float s = 0.f;
#pragma unroll
    for (int j = 0; j < 8; ++j) { f[j] = __expf(f[j] - m); s += f[j]; }
    red[tid] = s;
    __syncthreads();
#pragma unroll
    for (int q = 128; q > 0; q >>= 1) {
        if (tid < q) red[tid] += red[tid + q];
        __syncthreads();
    }
    const float inv = 1.0f / red[0];
    v0 = make_float4(f[0] * inv, f[1] * inv, f[2] * inv, f[3] * inv);
    v1 = make_float4(f[4] * inv, f[5] * inv, f[6] * inv, f[7] * inv);
    *(float4*)(p + tid * 8)     = v0;
    *(float4*)(p + tid * 8 + 4) = v1;
}

// ---------------------------------------------------------------------------
// PV: ctx[b, q, h*64+d] = sum_k P[b,h,q,k] * Vt[b,h,d,k]   (ctx bf16)
// ---------------------------------------------------------------------------
__global__ __launch_bounds__(256)
void k_pv(const float* __restrict__ P, const bf16* __restrict__ Vt,
          bf16* __restrict__ ctx)
{
    const int m0 = blockIdx.x * 64;
    const int bh = blockIdx.y;
    const int b = bh >> 4, h = bh & 15;
    const float* A  = P  + ((size_t)bh * SLQ + m0) * SLK;
    const bf16*  Bt = Vt + (size_t)bh * DHEAD * SLK;
    f32x4 z = {0.f, 0.f, 0.f, 0.f};
    f32x4 acc[2][2] = {{z, z}, {z, z}};
    gemm_core(A, SLK, Bt, SLK, SLK, acc);
    const int lane = threadIdx.x & 63;
    const int wave = threadIdx.x >> 6;
    const int wr = (wave >> 1) * 32, wc = (wave & 1) * 32;
#pragma unroll
    for (int i = 0; i < 2; ++i)
#pragma unroll
        for (int j = 0; j < 2; ++j) {
            const int d = wc + j * 16 + (lane & 15);
#pragma unroll
            for (int r = 0; r < 4; ++r) {
                const int q = m0 + wr + i * 16 + (lane >> 4) * 4 + r;
                ctx[((size_t)(b * SLQ + q)) * DMODEL + h * DHEAD + d] =
                    __float2bfloat16(acc[i][j][r]);
            }
        }
}

// ---------------------------------------------------------------------------
// Layout (all global I/O f32; intermediates bf16):
//   d_out:  out f32 [0 .. 8MB) ‖ attn f32 [8MB .. 276MB)
//   Qp  = d_out bytes [0 .. 4MB) as bf16   live: projQ -> k_scores (dead before
//                                          final out write)
//   Kp  = ws[0 .. 8MB)  bf16               live: projK -> k_scores
//   Vt  = ws[8 .. 16MB) bf16               live: projV -> k_pv
//   ctx = ws[0 .. 4MB)  bf16 (aliases dead Kp)  live: k_pv -> final proj
// Peak ws = 16 MB.
// ---------------------------------------------------------------------------
extern "C" void kernel_launch(void* const* d_in, const int* in_sizes, int n_in,
                              void* d_out, int out_size, void* d_ws, size_t ws_size,
                              hipStream_t stream)
{
    const float* query = (const float*)d_in[0];
    const float* key   = (const float*)d_in[1];
    const float* value = (const float*)d_in[2];
    const int*   mask  = (const int*)d_in[3];
    const float* bias  = (const float*)d_in[4];
    const float* Wq = (const float*)d_in[5];
    const float* bq = (const float*)d_in[6];
    const float* Wk = (const float*)d_in[7];
    const float* bk = (const float*)d_in[8];
    const float* Wv = (const float*)d_in[9];
    const float* bv = (const float*)d_in[10];
    const float* Wo = (const float*)d_in[11];
    const float* bo = (const float*)d_in[12];

    float* out  = (float*)d_out;            // [B, Lq, D] f32
    float* attn = out + OUTQ;               // [B, H, Lq, Lk] f32

    bf16* Qp  = (bf16*)d_out;               // borrow out region (4MB of 8MB)
    bf16* Kp  = (bf16*)d_ws;                // 4M elems (8MB)
    bf16* Vt  = Kp + (size_t)BATCH * SLK * DMODEL;  // 4M elems (8MB)
    bf16* ctx = (bf16*)d_ws;                // 2M elems, aliases dead Kp

    dim3 blk(256);

    k_proj<float, bf16><<<dim3(BATCH * SLQ / 64, DMODEL / 64), blk, 0, stream>>>(query, Wq, bq, Qp, DMODEL, DMODEL);
    k_proj<float, bf16><<<dim3(BATCH * SLK / 64, DMODEL / 64), blk, 0, stream>>>(key,   Wk, bk, Kp, DMODEL, DMODEL);
    k_projV<<<dim3(BATCH * SLK / 64, DMODEL / 64), blk, 0, stream>>>(value, Wv, bv, Vt);
    k_scores<<<dim3(SLQ / 64, SLK / 64, BATCH * NHEADS), blk, 0, stream>>>(Qp, Kp, bias, mask, attn);
    k_softmax<<<dim3(BATCH * NHEADS * SLQ), blk, 0, stream>>>(attn);
    k_pv<<<dim3(SLQ / 64, BATCH * NHEADS), blk, 0, stream>>>(attn, Vt, ctx);
    k_proj<bf16, float><<<dim3(BATCH * SLQ / 64, DMODEL / 64), blk, 0, stream>>>(ctx, Wo, bo, out, DMODEL, DMODEL);
}